// Round 10
// baseline (124.307 us; speedup 1.0000x reference)
//
#include <hip/hip_runtime.h>
#include <math.h>

// Problem constants (from reference setup_inputs)
#define BS 64      // batch
#define F  256     // features (K of the Gram matmul)
#define M  128     // columns  (M=N of the Gram matmul)
#define MF (M * F) // u16 elements per matrix in hT
#define NBP 1056   // blocks per mat: sum_a ceil((64-a)/2)  (= 8 * 132)

typedef unsigned short u16;
typedef _Float16 f16x8 __attribute__((ext_vector_type(8)));
typedef float    f32x16 __attribute__((ext_vector_type(16)));

// ---------------------------------------------------------------------------
// Pre-pass: fp32 [f][m] -> fp16 GRANULE-MAJOR hT[b][f8][m][8]. (rounds 6-9:
// verified; coalesced layout was worth 107->58 us when staging through LDS.)
// The same layout makes DIRECT per-lane fragment loads coalesced: fragment
// (kb fixed, m = t*32 + lane31) = contiguous 512 B per half-wave.
// ---------------------------------------------------------------------------
__global__ __launch_bounds__(256) void convert_f16_kernel(
    const float* __restrict__ m1, const float* __restrict__ m2,
    u16* __restrict__ hT)
{
    __shared__ float tile[64 * M];   // 32 KB
    const int mat = blockIdx.x >> 6;
    const int b   = blockIdx.x & 63;
    const int f0  = blockIdx.y * 64;
    const float* src = (mat == 0 ? m1 : m2) + (size_t)b * MF + (size_t)f0 * M;
    const int tid = threadIdx.x;

    const float4* g = (const float4*)src;
    float4* s = (float4*)tile;
    #pragma unroll
    for (int i = 0; i < 8; ++i)
        s[tid + i * 256] = g[tid + i * 256];
    __syncthreads();

    const size_t obase = ((size_t)(mat * BS + b) * 32 + (f0 >> 3)) * 1024;
    #pragma unroll
    for (int it = 0; it < 4; ++it) {
        const int idx = it * 256 + tid;
        const int f8l = idx >> 7;
        const int m   = idx & 127;
        u16 hh[8] __attribute__((aligned(16)));
        #pragma unroll
        for (int j = 0; j < 8; ++j) {
            const float x = tile[(f8l * 8 + j) * M + m];  // 2 lanes/bank: free
            const _Float16 h = (_Float16)x;               // RNE
            hh[j] = __builtin_bit_cast(u16, h);
        }
        *(uint4*)&hT[obase + (size_t)idx * 8] = *(const uint4*)hh;
    }
}

// ---------------------------------------------------------------------------
// One block per (a, b-pair): pairs (a,b1),(a,b2=b1+1) share A. 4 waves;
// wave w = (pp=w>>1, c=w&1) computes a 128x64 region of pair pp
// (acc = 8 x f32x16 = 128 AGPR, 2 waves/SIMD).
// NO LDS, NO K-loop barriers: with granule-major hT, each lane's MFMA
// fragment is a coalesced 16B global load (16 cache lines per wave-load,
// the optimum). Rounds 6-9 showed the LDS port (~23 us/CU) + barrier-phase
// stalls bound the staged design; this moves operand delivery to the
// L1/L2 path and lets the compiler interleave MFMA with loads via
// fine-grained vmcnt (no barrier ever drains the queue).
// Round-4's version of this idea failed ONLY because hT was row-major
// (32 lines per load); the granule layout fixes exactly that.
// ---------------------------------------------------------------------------
__global__ __launch_bounds__(256, 2) void gram_hist_mfma(
    const u16* __restrict__ hT, float* __restrict__ out)
{
    __shared__ float smin[4], smax[4];
    __shared__ int hist[2][8];

    const int tid  = threadIdx.x;
    const int lane = tid & 63;
    const int w    = tid >> 6;

    if (tid < 16) hist[tid >> 3][tid & 7] = 0;

    // XCD swizzle: dispatch round-robins consecutive blockIdx across 8 XCDs;
    // remap so each XCD gets a contiguous run of 132 pair-jobs (shared `a`
    // matrices stay in one XCD's L2). Perf heuristic only (G16-safe).
    const int bx = blockIdx.x;
    int p = (bx & 7) * 132 + (bx >> 3);
    int a = 0;
    { int cnt = 32; while (p >= cnt) { p -= cnt; ++a; cnt = (64 - a + 1) >> 1; } }
    const int b1 = a + 2 * p;
    int b2 = b1 + 1;
    const bool b2valid = (b2 <= 63);
    if (!b2valid) b2 = b1;          // duplicate work, writes suppressed
    const int mat = blockIdx.y;

    const int pp = w >> 1;     // which pair (0: b1, 1: b2)
    const int c  = w & 1;      // which 64-col half
    const int l31   = lane & 31;
    const int lhalf = lane >> 5;

    const u16* Abase = hT + (size_t)(mat * BS + a) * MF;
    const u16* Bbase = hT + (size_t)(mat * BS + (pp == 0 ? b1 : b2)) * MF;

    // Fragment base pointers. Granule layout: u16 offset of (kb, m) granule
    // = kb*1024 + m*8. Fragment for MFMA at k-step kk uses kb = kk*2 + lhalf.
    const u16* pa = Abase + lhalf * 1024 + l31 * 8;            // + t*256 + kk*2048
    const u16* pb = Bbase + lhalf * 1024 + (c * 64 + l31) * 8; // + t*256 + kk*2048

    f32x16 acc[4][2];
    #pragma unroll
    for (int ti = 0; ti < 4; ++ti)
        #pragma unroll
        for (int u = 0; u < 2; ++u)
            #pragma unroll
            for (int r = 0; r < 16; ++r) acc[ti][u][r] = 0.0f;

    // 16 k-steps, fully unrolled, no barriers: compiler pipelines loads
    // ahead of MFMA with fine-grained vmcnt.
    #pragma unroll
    for (int kk = 0; kk < 16; ++kk) {
        const int ko = kk * 2048;
        const f16x8 a0 = *(const f16x8*)(pa + ko);
        const f16x8 a1 = *(const f16x8*)(pa + ko + 256);
        const f16x8 a2 = *(const f16x8*)(pa + ko + 512);
        const f16x8 a3 = *(const f16x8*)(pa + ko + 768);
        const f16x8 b0 = *(const f16x8*)(pb + ko);
        const f16x8 b1f = *(const f16x8*)(pb + ko + 256);
        acc[0][0] = __builtin_amdgcn_mfma_f32_32x32x16_f16(a0, b0,  acc[0][0], 0, 0, 0);
        acc[0][1] = __builtin_amdgcn_mfma_f32_32x32x16_f16(a0, b1f, acc[0][1], 0, 0, 0);
        acc[1][0] = __builtin_amdgcn_mfma_f32_32x32x16_f16(a1, b0,  acc[1][0], 0, 0, 0);
        acc[1][1] = __builtin_amdgcn_mfma_f32_32x32x16_f16(a1, b1f, acc[1][1], 0, 0, 0);
        acc[2][0] = __builtin_amdgcn_mfma_f32_32x32x16_f16(a2, b0,  acc[2][0], 0, 0, 0);
        acc[2][1] = __builtin_amdgcn_mfma_f32_32x32x16_f16(a2, b1f, acc[2][1], 0, 0, 0);
        acc[3][0] = __builtin_amdgcn_mfma_f32_32x32x16_f16(a3, b0,  acc[3][0], 0, 0, 0);
        acc[3][1] = __builtin_amdgcn_mfma_f32_32x32x16_f16(a3, b1f, acc[3][1], 0, 0, 0);
    }

    // ---- epilogue: pair pp owned by waves (pp,c=0),(pp,c=1) ----
    float vmin = acc[0][0][0], vmax = vmin;
    #pragma unroll
    for (int ti = 0; ti < 4; ++ti)
        #pragma unroll
        for (int u = 0; u < 2; ++u)
            #pragma unroll
            for (int r = 0; r < 16; ++r) {
                vmin = fminf(vmin, acc[ti][u][r]);
                vmax = fmaxf(vmax, acc[ti][u][r]);
            }
    #pragma unroll
    for (int off = 1; off < 64; off <<= 1) {
        vmin = fminf(vmin, __shfl_xor(vmin, off, 64));
        vmax = fmaxf(vmax, __shfl_xor(vmax, off, 64));
    }
    if (lane == 0) { smin[w] = vmin; smax[w] = vmax; }
    __syncthreads();
    const float pmn = fminf(smin[pp * 2], smin[pp * 2 + 1]);
    const float pmx = fmaxf(smax[pp * 2], smax[pp * 2 + 1]);
    const float denom = (pmx > pmn) ? (pmx - pmn) : 1.0f;
    const float scale = 8.0f / denom;
    const float bias  = -pmn * scale;

    // per-thread packed histogram: 128 values -> 8-bit fields (<=128/bin)
    unsigned w0 = 0, w1 = 0;
    #pragma unroll
    for (int ti = 0; ti < 4; ++ti)
        #pragma unroll
        for (int u = 0; u < 2; ++u)
            #pragma unroll
            for (int r = 0; r < 16; ++r) {
                const float t = fmaf(acc[ti][u][r], scale, bias);
                int k = (int)t;          // t >= -eps; trunc == floor
                k = k > 7 ? 7 : k;
                const unsigned inc = 1u << ((k & 3) * 8);
                if (k < 4) w0 += inc; else w1 += inc;
            }
    unsigned e0 = (w0 & 0xFFu)         | (((w0 >> 8)  & 0xFFu) << 16);
    unsigned e1 = ((w0 >> 16) & 0xFFu) | (((w0 >> 24) & 0xFFu) << 16);
    unsigned e2 = (w1 & 0xFFu)         | (((w1 >> 8)  & 0xFFu) << 16);
    unsigned e3 = ((w1 >> 16) & 0xFFu) | (((w1 >> 24) & 0xFFu) << 16);
    #pragma unroll
    for (int off = 32; off > 0; off >>= 1) {
        e0 += __shfl_down(e0, off, 64);
        e1 += __shfl_down(e1, off, 64);
        e2 += __shfl_down(e2, off, 64);
        e3 += __shfl_down(e3, off, 64);
    }
    if (lane == 0) {
        atomicAdd(&hist[pp][0], (int)(e0 & 0xFFFFu)); atomicAdd(&hist[pp][1], (int)(e0 >> 16));
        atomicAdd(&hist[pp][2], (int)(e1 & 0xFFFFu)); atomicAdd(&hist[pp][3], (int)(e1 >> 16));
        atomicAdd(&hist[pp][4], (int)(e2 & 0xFFFFu)); atomicAdd(&hist[pp][5], (int)(e2 >> 16));
        atomicAdd(&hist[pp][6], (int)(e3 & 0xFFFFu)); atomicAdd(&hist[pp][7], (int)(e3 >> 16));
    }
    __syncthreads();

    // one wave per pair normalizes and writes both symmetric rows
    const int B = (pp == 0) ? b1 : b2;
    const bool valid = (pp == 0) || b2valid;
    if (valid && c == 0 && lane < 8) {
        float ss = 0.0f;
        #pragma unroll
        for (int k = 0; k < 8; ++k) {
            const float cc = (float)hist[pp][k];
            ss += cc * cc;
        }
        const float nrm = fmaxf(sqrtf(ss), 1e-12f);
        const float v = (float)hist[pp][lane] / nrm;
        out[((size_t)a * BS + B) * 16 + mat * 8 + lane] = v;
        if (a != B)
            out[((size_t)B * BS + a) * 16 + mat * 8 + lane] = v;
    }
}

extern "C" void kernel_launch(void* const* d_in, const int* in_sizes, int n_in,
                              void* d_out, int out_size, void* d_ws, size_t ws_size,
                              hipStream_t stream) {
    const float* m1 = (const float*)d_in[0];
    const float* m2 = (const float*)d_in[1];
    float* out = (float*)d_out;

    // Workspace: granule-major fp16 array, 2*64*128*256 u16 = 8.39 MB.
    u16* hT = (u16*)d_ws;

    convert_f16_kernel<<<dim3(128, 4), 256, 0, stream>>>(m1, m2, hT);
    gram_hist_mfma<<<dim3(NBP, 2), 256, 0, stream>>>(hT, out);
}

// Round 11
// 120.690 us; speedup vs baseline: 1.0300x; 1.0300x over previous
//
#include <hip/hip_runtime.h>
#include <math.h>

// Problem constants (from reference setup_inputs)
#define BS 64      // batch
#define F  256     // features (K of the Gram matmul)
#define M  128     // columns  (M=N of the Gram matmul)
#define MF (M * F) // u16 elements per matrix in hT
#define NBP 1056   // blocks per mat: sum_a ceil((64-a)/2)

typedef unsigned short u16;
typedef _Float16 f16x8 __attribute__((ext_vector_type(8)));
typedef float    f32x16 __attribute__((ext_vector_type(16)));

// ---------------------------------------------------------------------------
// Pre-pass: fp32 [f][m] -> fp16 GRANULE-MAJOR hT[b][f8][m][8]. (rounds 6-9:
// verified, coalesced both sides.)
// ---------------------------------------------------------------------------
__global__ __launch_bounds__(256) void convert_f16_kernel(
    const float* __restrict__ m1, const float* __restrict__ m2,
    u16* __restrict__ hT)
{
    __shared__ float tile[64 * M];   // 32 KB
    const int mat = blockIdx.x >> 6;
    const int b   = blockIdx.x & 63;
    const int f0  = blockIdx.y * 64;
    const float* src = (mat == 0 ? m1 : m2) + (size_t)b * MF + (size_t)f0 * M;
    const int tid = threadIdx.x;

    const float4* g = (const float4*)src;
    float4* s = (float4*)tile;
    #pragma unroll
    for (int i = 0; i < 8; ++i)
        s[tid + i * 256] = g[tid + i * 256];
    __syncthreads();

    const size_t obase = ((size_t)(mat * BS + b) * 32 + (f0 >> 3)) * 1024;
    #pragma unroll
    for (int it = 0; it < 4; ++it) {
        const int idx = it * 256 + tid;
        const int f8l = idx >> 7;
        const int m   = idx & 127;
        u16 hh[8] __attribute__((aligned(16)));
        #pragma unroll
        for (int j = 0; j < 8; ++j) {
            const float x = tile[(f8l * 8 + j) * M + m];  // 2 lanes/bank: free
            const _Float16 h = (_Float16)x;               // RNE
            hh[j] = __builtin_bit_cast(u16, h);
        }
        *(uint4*)&hT[obase + (size_t)idx * 8] = *(const uint4*)hh;
    }
}

// ---------------------------------------------------------------------------
// One block = 512 threads = 8 waves, 2 pairs (a,b1),(a,b2=b1+1) sharing A.
// Wave w: pp=w>>2 (pair), rr=(w>>1)&1 (row half), cc=w&1 (col half) ->
// 64x64 C-quadrant, acc = 4 x f32x16 = 64 AGPR.
// Combination of the two individually-proven pieces:
//  * r9's REGISTER pipeline (3 named uint4/thread; global->VGPR at iter top,
//    MFMA covers latency, ds_write->alt buffer, barrier orders LDS only --
//    no vmcnt(0) DMA drain).
//  * r7's 4-waves/SIMD geometry (64 AGPR + ~60 VGPR < 128 regs/wave ->
//    16 waves/CU, 2 blocks/CU) so co-resident waves cover barrier phases.
// r7 failed only because DMA drains scaled with wave count; r9 was neutral
// only because 2 waves/SIMD couldn't overlap the write phase. LDS: double-
// buffered [buf][{A,B1,B2} 8KB] = 48 KB, granule-major == global layout.
// ---------------------------------------------------------------------------
__global__ __launch_bounds__(512, 4) void gram_hist_mfma(
    const u16* __restrict__ hT, float* __restrict__ out)
{
    __shared__ u16 lds[2 * 12288];   // 48 KB
    __shared__ float smin[8], smax[8];
    __shared__ int hist[2][8];

    const int tid  = threadIdx.x;
    const int lane = tid & 63;
    const int w    = tid >> 6;

    if (tid < 16) hist[tid >> 3][tid & 7] = 0;

    // Decode blockIdx.x -> (a, p) with per-a count ceil((64-a)/2).
    int p = blockIdx.x, a = 0;
    { int cnt = 32; while (p >= cnt) { p -= cnt; ++a; cnt = (64 - a + 1) >> 1; } }
    const int b1 = a + 2 * p;
    int b2 = b1 + 1;
    const bool b2valid = (b2 <= 63);
    if (!b2valid) b2 = b1;          // duplicate work, writes suppressed
    const int mat = blockIdx.y;

    // Per-thread staging source pointers: one granule (16B) per matrix per
    // chunk; chunk advance = 4096 u16.
    const u16* pa  = hT + (size_t)(mat * BS + a)  * MF + tid * 8;
    const u16* pb1 = hT + (size_t)(mat * BS + b1) * MF + tid * 8;
    const u16* pb2 = hT + (size_t)(mat * BS + b2) * MF + tid * 8;

    const int pp = w >> 2;          // pair (0: b1, 1: b2)
    const int rr = (w >> 1) & 1;    // row half
    const int cc = w & 1;           // col half
    const int l31   = lane & 31;
    const int lhalf = lane >> 5;

    const int d0 = tid * 8;         // LDS dest (u16) within A region

    f32x16 acc[2][2];
    #pragma unroll
    for (int ti = 0; ti < 2; ++ti)
        #pragma unroll
        for (int tj = 0; tj < 2; ++tj)
            #pragma unroll
            for (int r = 0; r < 16; ++r) acc[ti][tj][r] = 0.0f;

    // ---- prologue: chunk 0 ----
    uint4 s0 = *(const uint4*)(pa);
    uint4 s1 = *(const uint4*)(pb1);
    uint4 s2 = *(const uint4*)(pb2);
    *(uint4*)&lds[d0]        = s0;
    *(uint4*)&lds[4096 + d0] = s1;
    *(uint4*)&lds[8192 + d0] = s2;
    __syncthreads();

    for (int it = 0; it < 8; ++it) {
        const int cur = (it & 1) * 12288;
        const int alt = cur ^ 12288;

        if (it < 7) {   // global->VGPR for chunk it+1; latency hidden by MFMA
            const int koff = (it + 1) * 4096;
            s0 = *(const uint4*)(pa  + koff);
            s1 = *(const uint4*)(pb1 + koff);
            s2 = *(const uint4*)(pb2 + koff);
        }

        #pragma unroll
        for (int kk = 0; kk < 2; ++kk) {
            const int kb = kk * 2 + lhalf;
            f16x8 af[2], bf[2];
            #pragma unroll
            for (int t = 0; t < 2; ++t) {
                af[t] = *(const f16x8*)&lds[cur + (kb * 128 + rr * 64 + t * 32 + l31) * 8];
                bf[t] = *(const f16x8*)&lds[cur + (1 + pp) * 4096 + (kb * 128 + cc * 64 + t * 32 + l31) * 8];
            }
            #pragma unroll
            for (int ti = 0; ti < 2; ++ti)
                #pragma unroll
                for (int tj = 0; tj < 2; ++tj)
                    acc[ti][tj] = __builtin_amdgcn_mfma_f32_32x32x16_f16(af[ti], bf[tj], acc[ti][tj], 0, 0, 0);
        }

        if (it < 7) {   // VGPR->LDS (alt buffer); loads landed during MFMA
            *(uint4*)&lds[alt + d0]        = s0;
            *(uint4*)&lds[alt + 4096 + d0] = s1;
            *(uint4*)&lds[alt + 8192 + d0] = s2;
        }
        __syncthreads();   // orders LDS writes only
    }

    // ---- epilogue: pair pp owned by 4 waves (rr,cc) ----
    float vmin = acc[0][0][0], vmax = vmin;
    #pragma unroll
    for (int ti = 0; ti < 2; ++ti)
        #pragma unroll
        for (int tj = 0; tj < 2; ++tj)
            #pragma unroll
            for (int r = 0; r < 16; ++r) {
                vmin = fminf(vmin, acc[ti][tj][r]);
                vmax = fmaxf(vmax, acc[ti][tj][r]);
            }
    #pragma unroll
    for (int off = 1; off < 64; off <<= 1) {
        vmin = fminf(vmin, __shfl_xor(vmin, off, 64));
        vmax = fmaxf(vmax, __shfl_xor(vmax, off, 64));
    }
    if (lane == 0) { smin[w] = vmin; smax[w] = vmax; }
    __syncthreads();
    const int hb = pp * 4;
    const float pmn = fminf(fminf(smin[hb], smin[hb + 1]), fminf(smin[hb + 2], smin[hb + 3]));
    const float pmx = fmaxf(fmaxf(smax[hb], smax[hb + 1]), fmaxf(smax[hb + 2], smax[hb + 3]));
    const float denom = (pmx > pmn) ? (pmx - pmn) : 1.0f;
    const float scale = 8.0f / denom;
    const float bias  = -pmn * scale;

    // per-thread packed histogram: 64 values -> 8-bit fields (<=64/bin)
    unsigned w0 = 0, w1 = 0;
    #pragma unroll
    for (int ti = 0; ti < 2; ++ti)
        #pragma unroll
        for (int tj = 0; tj < 2; ++tj)
            #pragma unroll
            for (int r = 0; r < 16; ++r) {
                const float t = fmaf(acc[ti][tj][r], scale, bias);
                int k = (int)t;          // t >= -eps; trunc == floor
                k = k > 7 ? 7 : k;
                const unsigned inc = 1u << ((k & 3) * 8);
                if (k < 4) w0 += inc; else w1 += inc;
            }
    unsigned e0 = (w0 & 0xFFu)         | (((w0 >> 8)  & 0xFFu) << 16);
    unsigned e1 = ((w0 >> 16) & 0xFFu) | (((w0 >> 24) & 0xFFu) << 16);
    unsigned e2 = (w1 & 0xFFu)         | (((w1 >> 8)  & 0xFFu) << 16);
    unsigned e3 = ((w1 >> 16) & 0xFFu) | (((w1 >> 24) & 0xFFu) << 16);
    #pragma unroll
    for (int off = 32; off > 0; off >>= 1) {
        e0 += __shfl_down(e0, off, 64);
        e1 += __shfl_down(e1, off, 64);
        e2 += __shfl_down(e2, off, 64);
        e3 += __shfl_down(e3, off, 64);
    }
    if (lane == 0) {
        atomicAdd(&hist[pp][0], (int)(e0 & 0xFFFFu)); atomicAdd(&hist[pp][1], (int)(e0 >> 16));
        atomicAdd(&hist[pp][2], (int)(e1 & 0xFFFFu)); atomicAdd(&hist[pp][3], (int)(e1 >> 16));
        atomicAdd(&hist[pp][4], (int)(e2 & 0xFFFFu)); atomicAdd(&hist[pp][5], (int)(e2 >> 16));
        atomicAdd(&hist[pp][6], (int)(e3 & 0xFFFFu)); atomicAdd(&hist[pp][7], (int)(e3 >> 16));
    }
    __syncthreads();

    // one wave per pair normalizes and writes both symmetric rows
    const int B = (pp == 0) ? b1 : b2;
    const bool valid = (pp == 0) || b2valid;
    if (valid && rr == 0 && cc == 0 && lane < 8) {
        float ss = 0.0f;
        #pragma unroll
        for (int k = 0; k < 8; ++k) {
            const float c = (float)hist[pp][k];
            ss += c * c;
        }
        const float nrm = fmaxf(sqrtf(ss), 1e-12f);
        const float v = (float)hist[pp][lane] / nrm;
        out[((size_t)a * BS + B) * 16 + mat * 8 + lane] = v;
        if (a != B)
            out[((size_t)B * BS + a) * 16 + mat * 8 + lane] = v;
    }
}

extern "C" void kernel_launch(void* const* d_in, const int* in_sizes, int n_in,
                              void* d_out, int out_size, void* d_ws, size_t ws_size,
                              hipStream_t stream) {
    const float* m1 = (const float*)d_in[0];
    const float* m2 = (const float*)d_in[1];
    float* out = (float*)d_out;

    // Workspace: granule-major fp16 array, 2*64*128*256 u16 = 8.39 MB.
    u16* hT = (u16*)d_ws;

    convert_f16_kernel<<<dim3(128, 4), 256, 0, stream>>>(m1, m2, hT);
    gram_hist_mfma<<<dim3(NBP, 2), 512, 0, stream>>>(hT, out);
}

// Round 12
// 119.389 us; speedup vs baseline: 1.0412x; 1.0109x over previous
//
#include <hip/hip_runtime.h>
#include <math.h>

// Problem constants (from reference setup_inputs)
#define BS 64      // batch
#define F  256     // features (K of the Gram matmul)
#define M  128     // columns  (M=N of the Gram matmul)
#define MF (M * F) // u16 elements per matrix in hT
#define NBP 1056   // blocks per mat: sum_a ceil((64-a)/2)

typedef unsigned short u16;
typedef _Float16 f16x8 __attribute__((ext_vector_type(8)));
typedef float    f32x16 __attribute__((ext_vector_type(16)));

// ---------------------------------------------------------------------------
// Pre-pass: fp32 [f][m] -> fp16 GRANULE-MAJOR hT[b][f8][m][8]. (rounds 6-11:
// verified, coalesced both sides, absmax 0.0039.)
// ---------------------------------------------------------------------------
__global__ __launch_bounds__(256) void convert_f16_kernel(
    const float* __restrict__ m1, const float* __restrict__ m2,
    u16* __restrict__ hT)
{
    __shared__ float tile[64 * M];   // 32 KB
    const int mat = blockIdx.x >> 6;
    const int b   = blockIdx.x & 63;
    const int f0  = blockIdx.y * 64;
    const float* src = (mat == 0 ? m1 : m2) + (size_t)b * MF + (size_t)f0 * M;
    const int tid = threadIdx.x;

    const float4* g = (const float4*)src;
    float4* s = (float4*)tile;
    #pragma unroll
    for (int i = 0; i < 8; ++i)
        s[tid + i * 256] = g[tid + i * 256];
    __syncthreads();

    const size_t obase = ((size_t)(mat * BS + b) * 32 + (f0 >> 3)) * 1024;
    #pragma unroll
    for (int it = 0; it < 4; ++it) {
        const int idx = it * 256 + tid;
        const int f8l = idx >> 7;
        const int m   = idx & 127;
        u16 hh[8] __attribute__((aligned(16)));
        #pragma unroll
        for (int j = 0; j < 8; ++j) {
            const float x = tile[(f8l * 8 + j) * M + m];  // 2 lanes/bank: free
            const _Float16 h = (_Float16)x;               // RNE
            hh[j] = __builtin_bit_cast(u16, h);
        }
        *(uint4*)&hT[obase + (size_t)idx * 8] = *(const uint4*)hh;
    }
}

// ---------------------------------------------------------------------------
// r6 geometry (best measured: 58.3 us): one block per (a, b-pair), pairs
// (a,b1),(a,b2=b1+1) share A; 4 waves, wave w=(pp=w>>1, c=w&1) computes a
// 128x64 region of pair pp; acc = 8 x f32x16 = 128 AGPR, 2 waves/SIMD.
// NEW: register pipeline with LONG lookahead. Per iteration:
//   barrier -> ds_write chunk it+1 (regs loaded LAST iteration)
//           -> issue global loads for chunk it+2
//           -> compute chunk it -> barrier
// Load->consume distance ~ one full iteration (~3500 cyc), covering L2/HBM
// latency (r6/r9 gave the loads only ~1100 cyc -- the measured ~2000
// cyc/chunk stall). Six NAMED uint4 regs, straight-line (r8's lambda/array
// scratch-demotion bug avoided; verify via WRITE_SIZE ~290 KB).
// LDS: double buffer [buf][{A,B1,B2} 8KB] = 48 KB, granule-major == global.
// ---------------------------------------------------------------------------
__global__ __launch_bounds__(256, 2) void gram_hist_mfma(
    const u16* __restrict__ hT, float* __restrict__ out)
{
    __shared__ u16 lds[2 * 12288];   // 48 KB
    __shared__ float smin[4], smax[4];
    __shared__ int hist[2][8];

    const int tid  = threadIdx.x;
    const int lane = tid & 63;
    const int w    = tid >> 6;

    if (tid < 16) hist[tid >> 3][tid & 7] = 0;

    // Decode blockIdx.x -> (a, p) with per-a count ceil((64-a)/2).
    int p = blockIdx.x, a = 0;
    { int cnt = 32; while (p >= cnt) { p -= cnt; ++a; cnt = (64 - a + 1) >> 1; } }
    const int b1 = a + 2 * p;
    int b2 = b1 + 1;
    const bool b2valid = (b2 <= 63);
    if (!b2valid) b2 = b1;          // duplicate work, writes suppressed
    const int mat = blockIdx.y;

    // Per-thread staging pointers: 2 granules (16B each) per matrix per chunk.
    const u16* pa  = hT + (size_t)(mat * BS + a)  * MF + tid * 8;
    const u16* pb1 = hT + (size_t)(mat * BS + b1) * MF + tid * 8;
    const u16* pb2 = hT + (size_t)(mat * BS + b2) * MF + tid * 8;

    const int pp = w >> 1;     // pair (0: b1, 1: b2)
    const int c  = w & 1;      // 64-col half
    const int l31   = lane & 31;
    const int lhalf = lane >> 5;

    const int d0 = tid * 8;            // LDS dest (u16): granule 1 of 2
    const int d1 = (256 + tid) * 8;    // granule 2 of 2

    f32x16 acc[4][2];
    #pragma unroll
    for (int ti = 0; ti < 4; ++ti)
        #pragma unroll
        for (int u = 0; u < 2; ++u)
            #pragma unroll
            for (int r = 0; r < 16; ++r) acc[ti][u][r] = 0.0f;

    // ---- prologue: chunk 0 direct to LDS; chunk 1 into regs ----
    uint4 r0 = *(const uint4*)(pa);
    uint4 r1 = *(const uint4*)(pa + 2048);
    uint4 r2 = *(const uint4*)(pb1);
    uint4 r3 = *(const uint4*)(pb1 + 2048);
    uint4 r4 = *(const uint4*)(pb2);
    uint4 r5 = *(const uint4*)(pb2 + 2048);
    *(uint4*)&lds[d0]         = r0;
    *(uint4*)&lds[d1]         = r1;
    *(uint4*)&lds[4096 + d0]  = r2;
    *(uint4*)&lds[4096 + d1]  = r3;
    *(uint4*)&lds[8192 + d0]  = r4;
    *(uint4*)&lds[8192 + d1]  = r5;
    r0 = *(const uint4*)(pa  + 4096);
    r1 = *(const uint4*)(pa  + 4096 + 2048);
    r2 = *(const uint4*)(pb1 + 4096);
    r3 = *(const uint4*)(pb1 + 4096 + 2048);
    r4 = *(const uint4*)(pb2 + 4096);
    r5 = *(const uint4*)(pb2 + 4096 + 2048);
    __syncthreads();

    for (int it = 0; it < 8; ++it) {
        const int cur = (it & 1) * 12288;
        const int alt = cur ^ 12288;

        // ds_write chunk it+1 (loaded last iteration; latency long covered).
        // alt == the buffer computed at it-1; barrier at end of it-1 makes
        // overwriting it safe.
        if (it < 7) {
            *(uint4*)&lds[alt + d0]        = r0;
            *(uint4*)&lds[alt + d1]        = r1;
            *(uint4*)&lds[alt + 4096 + d0] = r2;
            *(uint4*)&lds[alt + 4096 + d1] = r3;
            *(uint4*)&lds[alt + 8192 + d0] = r4;
            *(uint4*)&lds[alt + 8192 + d1] = r5;
        }
        // Issue global loads for chunk it+2 (consumed at it+1's top).
        if (it < 6) {
            const int koff = (it + 2) * 4096;
            r0 = *(const uint4*)(pa  + koff);
            r1 = *(const uint4*)(pa  + koff + 2048);
            r2 = *(const uint4*)(pb1 + koff);
            r3 = *(const uint4*)(pb1 + koff + 2048);
            r4 = *(const uint4*)(pb2 + koff);
            r5 = *(const uint4*)(pb2 + koff + 2048);
        }

        #pragma unroll
        for (int kk = 0; kk < 2; ++kk) {
            const int kb = kk * 2 + lhalf;
            f16x8 af[4], bf[2];
            #pragma unroll
            for (int t = 0; t < 4; ++t)
                af[t] = *(const f16x8*)&lds[cur + (kb * 128 + t * 32 + l31) * 8];
            #pragma unroll
            for (int t = 0; t < 2; ++t)
                bf[t] = *(const f16x8*)&lds[cur + (1 + pp) * 4096 + (kb * 128 + c * 64 + t * 32 + l31) * 8];
            #pragma unroll
            for (int ti = 0; ti < 4; ++ti)
                #pragma unroll
                for (int u = 0; u < 2; ++u)
                    acc[ti][u] = __builtin_amdgcn_mfma_f32_32x32x16_f16(af[ti], bf[u], acc[ti][u], 0, 0, 0);
        }
        __syncthreads();
    }

    // ---- epilogue: pair pp owned by waves (pp,c=0),(pp,c=1) ----
    float vmin = acc[0][0][0], vmax = vmin;
    #pragma unroll
    for (int ti = 0; ti < 4; ++ti)
        #pragma unroll
        for (int u = 0; u < 2; ++u)
            #pragma unroll
            for (int r = 0; r < 16; ++r) {
                vmin = fminf(vmin, acc[ti][u][r]);
                vmax = fmaxf(vmax, acc[ti][u][r]);
            }
    #pragma unroll
    for (int off = 1; off < 64; off <<= 1) {
        vmin = fminf(vmin, __shfl_xor(vmin, off, 64));
        vmax = fmaxf(vmax, __shfl_xor(vmax, off, 64));
    }
    if (lane == 0) { smin[w] = vmin; smax[w] = vmax; }
    __syncthreads();
    const float pmn = fminf(smin[pp * 2], smin[pp * 2 + 1]);
    const float pmx = fmaxf(smax[pp * 2], smax[pp * 2 + 1]);
    const float denom = (pmx > pmn) ? (pmx - pmn) : 1.0f;
    const float scale = 8.0f / denom;
    const float bias  = -pmn * scale;

    // per-thread packed histogram: 128 values -> 8-bit fields (<=128/bin)
    unsigned w0 = 0, w1 = 0;
    #pragma unroll
    for (int ti = 0; ti < 4; ++ti)
        #pragma unroll
        for (int u = 0; u < 2; ++u)
            #pragma unroll
            for (int r = 0; r < 16; ++r) {
                const float t = fmaf(acc[ti][u][r], scale, bias);
                int k = (int)t;          // t >= -eps; trunc == floor
                k = k > 7 ? 7 : k;
                const unsigned inc = 1u << ((k & 3) * 8);
                if (k < 4) w0 += inc; else w1 += inc;
            }
    unsigned e0 = (w0 & 0xFFu)         | (((w0 >> 8)  & 0xFFu) << 16);
    unsigned e1 = ((w0 >> 16) & 0xFFu) | (((w0 >> 24) & 0xFFu) << 16);
    unsigned e2 = (w1 & 0xFFu)         | (((w1 >> 8)  & 0xFFu) << 16);
    unsigned e3 = ((w1 >> 16) & 0xFFu) | (((w1 >> 24) & 0xFFu) << 16);
    #pragma unroll
    for (int off = 32; off > 0; off >>= 1) {
        e0 += __shfl_down(e0, off, 64);
        e1 += __shfl_down(e1, off, 64);
        e2 += __shfl_down(e2, off, 64);
        e3 += __shfl_down(e3, off, 64);
    }
    if (lane == 0) {
        atomicAdd(&hist[pp][0], (int)(e0 & 0xFFFFu)); atomicAdd(&hist[pp][1], (int)(e0 >> 16));
        atomicAdd(&hist[pp][2], (int)(e1 & 0xFFFFu)); atomicAdd(&hist[pp][3], (int)(e1 >> 16));
        atomicAdd(&hist[pp][4], (int)(e2 & 0xFFFFu)); atomicAdd(&hist[pp][5], (int)(e2 >> 16));
        atomicAdd(&hist[pp][6], (int)(e3 & 0xFFFFu)); atomicAdd(&hist[pp][7], (int)(e3 >> 16));
    }
    __syncthreads();

    // one wave per pair normalizes and writes both symmetric rows
    const int B = (pp == 0) ? b1 : b2;
    const bool valid = (pp == 0) || b2valid;
    if (valid && c == 0 && lane < 8) {
        float ss = 0.0f;
        #pragma unroll
        for (int k = 0; k < 8; ++k) {
            const float cc = (float)hist[pp][k];
            ss += cc * cc;
        }
        const float nrm = fmaxf(sqrtf(ss), 1e-12f);
        const float v = (float)hist[pp][lane] / nrm;
        out[((size_t)a * BS + B) * 16 + mat * 8 + lane] = v;
        if (a != B)
            out[((size_t)B * BS + a) * 16 + mat * 8 + lane] = v;
    }
}

extern "C" void kernel_launch(void* const* d_in, const int* in_sizes, int n_in,
                              void* d_out, int out_size, void* d_ws, size_t ws_size,
                              hipStream_t stream) {
    const float* m1 = (const float*)d_in[0];
    const float* m2 = (const float*)d_in[1];
    float* out = (float*)d_out;

    // Workspace: granule-major fp16 array, 2*64*128*256 u16 = 8.39 MB.
    u16* hT = (u16*)d_ws;

    convert_f16_kernel<<<dim3(128, 4), 256, 0, stream>>>(m1, m2, hT);
    gram_hist_mfma<<<dim3(NBP, 2), 256, 0, stream>>>(hT, out);
}

// Round 13
// 119.008 us; speedup vs baseline: 1.0445x; 1.0032x over previous
//
#include <hip/hip_runtime.h>
#include <math.h>

// Problem constants (from reference setup_inputs)
#define BS 64      // batch
#define F  256     // features (K of the Gram matmul)
#define M  128     // columns  (M=N of the Gram matmul)
#define MF (M * F) // u16 elements per matrix in hT
#define NBP 1056   // blocks per mat: sum_a ceil((64-a)/2)

typedef unsigned short u16;
typedef _Float16 f16x8 __attribute__((ext_vector_type(8)));
typedef float    f32x16 __attribute__((ext_vector_type(16)));

// ---------------------------------------------------------------------------
// SESSION-BEST KERNEL (round 6, 58.3 us main / 120.7 us total) — restored.
// Ladder: 444 (fp32 VALU) -> 189 (bf16-split 3-pass MFMA) -> 86 (fp16 1-pass)
// -> 58 (granule-major layout => coalesced DMA staging). Variants measured
// and rejected: no-LDS direct loads (82, VMEM front-end), 64x64 tiles @ 4
// waves/SIMD (66.6, +33% LDS-port), register pipeline (60.3, neutral),
// 256x256 block tile (107, 1 wave/SIMD), long-lookahead pipeline (75.5,
// VGPR pressure). Residual stall is barrier-phase convergence + DMA drain,
// not addressable from HIP source on this structure (m97-plateau analog).
// ---------------------------------------------------------------------------

// Pre-pass: fp32 [f][m] -> fp16 GRANULE-MAJOR hT[b][f8][m][8]; LDS transpose,
// both global read and write coalesced. absmax 0.0039 (fp16 single-pass).
__global__ __launch_bounds__(256) void convert_f16_kernel(
    const float* __restrict__ m1, const float* __restrict__ m2,
    u16* __restrict__ hT)
{
    __shared__ float tile[64 * M];   // 32 KB
    const int mat = blockIdx.x >> 6;
    const int b   = blockIdx.x & 63;
    const int f0  = blockIdx.y * 64;
    const float* src = (mat == 0 ? m1 : m2) + (size_t)b * MF + (size_t)f0 * M;
    const int tid = threadIdx.x;

    const float4* g = (const float4*)src;
    float4* s = (float4*)tile;
    #pragma unroll
    for (int i = 0; i < 8; ++i)
        s[tid + i * 256] = g[tid + i * 256];
    __syncthreads();

    const size_t obase = ((size_t)(mat * BS + b) * 32 + (f0 >> 3)) * 1024;
    #pragma unroll
    for (int it = 0; it < 4; ++it) {
        const int idx = it * 256 + tid;
        const int f8l = idx >> 7;
        const int m   = idx & 127;
        u16 hh[8] __attribute__((aligned(16)));
        #pragma unroll
        for (int j = 0; j < 8; ++j) {
            const float x = tile[(f8l * 8 + j) * M + m];  // 2 lanes/bank: free
            const _Float16 h = (_Float16)x;               // RNE
            hh[j] = __builtin_bit_cast(u16, h);
        }
        *(uint4*)&hT[obase + (size_t)idx * 8] = *(const uint4*)hh;
    }
}

__device__ __forceinline__ void async16(const u16* g, u16* l) {
    __builtin_amdgcn_global_load_lds(
        (const __attribute__((address_space(1))) unsigned int*)g,
        (__attribute__((address_space(3))) unsigned int*)l, 16, 0, 0);
}

// One block per (a, b-pair): computes pairs (a,b1) and (a,b2=b1+1), sharing
// the A-tile. 4 waves; wave w = (pp=w>>1, c=w&1) computes a 128x64 region of
// pair pp; acc = 8 x f32x16 = 128 AGPR, 2 waves/SIMD. LDS double-buffered
// [buf][{A,B1,B2} 8KB] = 48 KB; global granule layout == LDS layout, so the
// global_load_lds staging is contiguous (16 lines/KB, coalescing optimum);
// ds_read_b128 fragments are conflict-free (0 in SQ_LDS_BANK_CONFLICT).
__global__ __launch_bounds__(256, 2) void gram_hist_mfma(
    const u16* __restrict__ hT, float* __restrict__ out)
{
    __shared__ u16 lds[2 * 12288];   // 48 KB
    __shared__ float smin[4], smax[4];
    __shared__ int hist[2][8];

    const int tid  = threadIdx.x;
    const int lane = tid & 63;
    const int w    = tid >> 6;

    if (tid < 16) hist[tid >> 3][tid & 7] = 0;

    // Decode blockIdx.x -> (a, p) with per-a count ceil((64-a)/2).
    int p = blockIdx.x, a = 0;
    { int cnt = 32; while (p >= cnt) { p -= cnt; ++a; cnt = (64 - a + 1) >> 1; } }
    const int b1 = a + 2 * p;
    int b2 = b1 + 1;
    const bool b2valid = (b2 <= 63);
    if (!b2valid) b2 = b1;          // duplicate work, writes suppressed
    const int mat = blockIdx.y;

    const u16* Asrc  = hT + (size_t)(mat * BS + a)  * MF;
    const u16* B1src = hT + (size_t)(mat * BS + b1) * MF;
    const u16* B2src = hT + (size_t)(mat * BS + b2) * MF;

    // Stage one 32-k chunk (A,B1,B2 = 3 x 8KB contiguous) into buffer bufo.
    auto stage = [&](int bufo, int k0) {
        const int koff = k0 * 128;   // u16 offset of the chunk within a matrix
        #pragma unroll
        for (int g = 0; g < 6; ++g) {
            const int idx = (g & 1) * 256 + tid;   // 0..511, lane-contiguous
            const u16* s = (g < 2 ? Asrc : (g < 4 ? B1src : B2src)) + koff + idx * 8;
            async16(s, &lds[bufo + (g >> 1) * 4096 + idx * 8]);
        }
    };

    const int pp = w >> 1;     // which pair (0: b1, 1: b2)
    const int c  = w & 1;      // which 64-col half
    const int l31   = lane & 31;
    const int lhalf = lane >> 5;

    f32x16 acc[4][2];
    #pragma unroll
    for (int ti = 0; ti < 4; ++ti)
        #pragma unroll
        for (int u = 0; u < 2; ++u)
            #pragma unroll
            for (int r = 0; r < 16; ++r) acc[ti][u][r] = 0.0f;

    stage(0, 0);
    __syncthreads();

    for (int it = 0; it < 8; ++it) {
        const int cur = (it & 1) * 12288;
        if (it < 7) stage(cur ^ 12288, (it + 1) * 32);   // prefetch next

        #pragma unroll
        for (int kk = 0; kk < 2; ++kk) {
            const int kb = kk * 2 + lhalf;
            f16x8 af[4], bf[2];
            #pragma unroll
            for (int t = 0; t < 4; ++t)
                af[t] = *(const f16x8*)&lds[cur + (kb * 128 + t * 32 + l31) * 8];
            #pragma unroll
            for (int t = 0; t < 2; ++t)
                bf[t] = *(const f16x8*)&lds[cur + (1 + pp) * 4096 + (kb * 128 + c * 64 + t * 32 + l31) * 8];
            #pragma unroll
            for (int ti = 0; ti < 4; ++ti)
                #pragma unroll
                for (int u = 0; u < 2; ++u)
                    acc[ti][u] = __builtin_amdgcn_mfma_f32_32x32x16_f16(af[ti], bf[u], acc[ti][u], 0, 0, 0);
        }
        __syncthreads();   // everyone done with cur; prefetch drained under compute
    }

    // ---- epilogue: pair pp owned by waves (pp,c=0),(pp,c=1) ----
    float vmin = acc[0][0][0], vmax = vmin;
    #pragma unroll
    for (int ti = 0; ti < 4; ++ti)
        #pragma unroll
        for (int u = 0; u < 2; ++u)
            #pragma unroll
            for (int r = 0; r < 16; ++r) {
                vmin = fminf(vmin, acc[ti][u][r]);
                vmax = fmaxf(vmax, acc[ti][u][r]);
            }
    #pragma unroll
    for (int off = 1; off < 64; off <<= 1) {
        vmin = fminf(vmin, __shfl_xor(vmin, off, 64));
        vmax = fmaxf(vmax, __shfl_xor(vmax, off, 64));
    }
    if (lane == 0) { smin[w] = vmin; smax[w] = vmax; }
    __syncthreads();
    const float pmn = fminf(smin[pp * 2], smin[pp * 2 + 1]);
    const float pmx = fmaxf(smax[pp * 2], smax[pp * 2 + 1]);
    const float denom = (pmx > pmn) ? (pmx - pmn) : 1.0f;
    const float scale = 8.0f / denom;
    const float bias  = -pmn * scale;

    // per-thread packed histogram: 128 values -> 8-bit fields (<=128/bin)
    unsigned w0 = 0, w1 = 0;
    #pragma unroll
    for (int ti = 0; ti < 4; ++ti)
        #pragma unroll
        for (int u = 0; u < 2; ++u)
            #pragma unroll
            for (int r = 0; r < 16; ++r) {
                const float t = fmaf(acc[ti][u][r], scale, bias);
                int k = (int)t;          // t >= -eps; trunc == floor
                k = k > 7 ? 7 : k;
                const unsigned inc = 1u << ((k & 3) * 8);
                if (k < 4) w0 += inc; else w1 += inc;
            }
    unsigned e0 = (w0 & 0xFFu)         | (((w0 >> 8)  & 0xFFu) << 16);
    unsigned e1 = ((w0 >> 16) & 0xFFu) | (((w0 >> 24) & 0xFFu) << 16);
    unsigned e2 = (w1 & 0xFFu)         | (((w1 >> 8)  & 0xFFu) << 16);
    unsigned e3 = ((w1 >> 16) & 0xFFu) | (((w1 >> 24) & 0xFFu) << 16);
    #pragma unroll
    for (int off = 32; off > 0; off >>= 1) {
        e0 += __shfl_down(e0, off, 64);
        e1 += __shfl_down(e1, off, 64);
        e2 += __shfl_down(e2, off, 64);
        e3 += __shfl_down(e3, off, 64);
    }
    if (lane == 0) {
        atomicAdd(&hist[pp][0], (int)(e0 & 0xFFFFu)); atomicAdd(&hist[pp][1], (int)(e0 >> 16));
        atomicAdd(&hist[pp][2], (int)(e1 & 0xFFFFu)); atomicAdd(&hist[pp][3], (int)(e1 >> 16));
        atomicAdd(&hist[pp][4], (int)(e2 & 0xFFFFu)); atomicAdd(&hist[pp][5], (int)(e2 >> 16));
        atomicAdd(&hist[pp][6], (int)(e3 & 0xFFFFu)); atomicAdd(&hist[pp][7], (int)(e3 >> 16));
    }
    __syncthreads();

    // one wave per pair normalizes and writes both symmetric rows
    const int B = (pp == 0) ? b1 : b2;
    const bool valid = (pp == 0) || b2valid;
    if (valid && c == 0 && lane < 8) {
        float ss = 0.0f;
        #pragma unroll
        for (int k = 0; k < 8; ++k) {
            const float cc = (float)hist[pp][k];
            ss += cc * cc;
        }
        const float nrm = fmaxf(sqrtf(ss), 1e-12f);
        const float v = (float)hist[pp][lane] / nrm;
        out[((size_t)a * BS + B) * 16 + mat * 8 + lane] = v;
        if (a != B)
            out[((size_t)B * BS + a) * 16 + mat * 8 + lane] = v;
    }
}

extern "C" void kernel_launch(void* const* d_in, const int* in_sizes, int n_in,
                              void* d_out, int out_size, void* d_ws, size_t ws_size,
                              hipStream_t stream) {
    const float* m1 = (const float*)d_in[0];
    const float* m2 = (const float*)d_in[1];
    float* out = (float*)d_out;

    // Workspace: granule-major fp16 array, 2*64*128*256 u16 = 8.39 MB.
    u16* hT = (u16*)d_ws;

    convert_f16_kernel<<<dim3(128, 4), 256, 0, stream>>>(m1, m2, hT);
    gram_hist_mfma<<<dim3(NBP, 2), 256, 0, stream>>>(hT, out);
}